// Round 8
// baseline (551.566 us; speedup 1.0000x reference)
//
#include <hip/hip_runtime.h>
#include <hip/hip_cooperative_groups.h>

namespace cg = cooperative_groups;

#define DCH 128
#define TPB 256
#define T_PART 2048      // edges per partition tile
#define CAPC 10240       // slots per coarse bucket (avg 8192, +22 sigma)

typedef short bf16x8 __attribute__((ext_vector_type(8)));
typedef float f32x4 __attribute__((ext_vector_type(4)));

__device__ inline unsigned short f2bf(float f) {
    unsigned int u = __float_as_uint(f);
    unsigned int r = (u + 0x7fffu + ((u >> 16) & 1u)) >> 16;
    return (unsigned short)r;
}

// Shared memory reused across phases (max ~14.4 KB -> 4 blocks/CU by LDS).
union SMem {
    struct {
        int hist[256], basex[256], curx[256], gb[256], wsum[4];
        unsigned int spack[T_PART];
        unsigned char sbuck[T_PART];
    } p1;
    struct {
        int base_[513];     // exclusive scan of per-dest counts
        int cur_[512];      // counts, then placement cursors
        int red[4];
        int bbase;
    } p2;
};

// ======================= cooperative mega-kernel =======================
// phase0: zero gcount + pack W into MFMA B-frag bf16 layout
// phase1: coarse partition (bucket = dest>>9, LDS counting sort, burst writes)
// phase2: bucket -> exact CSR (cnt/off/srow) via LDS hist + single-wave scan
// phase3: y = bf16((x@W) * rsqrt(deg+1)) via mfma_f32_16x16x32_bf16
// NOTE (R7 lesson): no random global atomics in barrier-heavy phases — the
// vmcnt(0) drain before each s_barrier serializes on atomic latency.
__global__ __launch_bounds__(TPB, 4) void k_mega(
        const float* __restrict__ x, const int* __restrict__ row,
        const int* __restrict__ col, const float* __restrict__ W,
        unsigned short* __restrict__ Wf, int* __restrict__ cnt,
        int* __restrict__ off, int* __restrict__ gcount,
        unsigned int* __restrict__ coarse, int* __restrict__ srow,
        unsigned short* __restrict__ y, int n, int E, int B, int ntiles, int nrt) {
    __shared__ SMem sm;
    cg::grid_group grid = cg::this_grid();

    int tid = threadIdx.x;
    int wv = tid >> 6, lane = tid & 63;

    // ---------------- phase 0 ----------------
    if (blockIdx.x == 0 && tid < B) gcount[tid] = 0;
    if (blockIdx.x >= 1 && blockIdx.x <= 8) {
        int frag = (blockIdx.x - 1) * 4 + wv;     // 0..31 = nt*4+ks
        int nt = frag >> 2, ks = frag & 3;
        int nn = nt * 16 + (lane & 15);
        int k0 = ks * 32 + ((lane >> 4) * 8);
        unsigned short tmp[8];
#pragma unroll
        for (int j = 0; j < 8; ++j) tmp[j] = f2bf(W[(size_t)(k0 + j) * DCH + nn]);
        *(uint4*)&Wf[((size_t)frag * 64 + lane) * 8] = *(const uint4*)tmp;
    }
    __threadfence();
    grid.sync();

    // ---------------- phase 1: partition ----------------
    for (int tile = blockIdx.x; tile < ntiles; tile += gridDim.x) {
        int base_e = tile * T_PART;
        int tileCnt = min(T_PART, E - base_e);

        sm.p1.hist[tid] = 0;
        __syncthreads();

        int er[8], ec[8];
#pragma unroll
        for (int i = 0; i < 8; ++i) {
            int e = base_e + tid + i * TPB;
            if (e < E) {
                er[i] = row[e];
                ec[i] = col[e];
                atomicAdd(&sm.p1.hist[ec[i] >> 9], 1);
            } else {
                er[i] = -1;
                ec[i] = 0;
            }
        }
        __syncthreads();

        // exclusive scan over hist[256]: per-wave shfl + cross-wave offsets
        int v = sm.p1.hist[tid];
        int xs = v;
#pragma unroll
        for (int o = 1; o < 64; o <<= 1) {
            int t = __shfl_up(xs, o, 64);
            if (lane >= o) xs += t;
        }
        if (lane == 63) sm.p1.wsum[wv] = xs;
        __syncthreads();
        int add = 0;
        for (int w = 0; w < wv; ++w) add += sm.p1.wsum[w];
        int excl = xs - v + add;
        sm.p1.basex[tid] = excl;
        sm.p1.curx[tid] = excl;
        sm.p1.gb[tid] = (tid < B && v > 0) ? atomicAdd(&gcount[tid], v) : 0;
        __syncthreads();

#pragma unroll
        for (int i = 0; i < 8; ++i) {
            if (er[i] >= 0) {
                int bk = ec[i] >> 9;
                int slot = atomicAdd(&sm.p1.curx[bk], 1);
                sm.p1.spack[slot] = ((unsigned int)er[i] << 9) | (unsigned int)(ec[i] & 511);
                sm.p1.sbuck[slot] = (unsigned char)bk;
            }
        }
        __syncthreads();

        for (int s = tid; s < tileCnt; s += TPB) {
            int bk = sm.p1.sbuck[s];
            int dst = sm.p1.gb[bk] + (s - sm.p1.basex[bk]);
            if (dst < CAPC) coarse[(size_t)bk * CAPC + dst] = sm.p1.spack[s];
        }
        __syncthreads();
    }
    __threadfence();
    grid.sync();

    // ---------------- phase 2: bucket -> CSR ----------------
    for (int bk = blockIdx.x; bk < B; bk += gridDim.x) {
        // bbase = sum of min(gcount[i],CAPC) for i<bk
        int part = 0;
        for (int i = tid; i < bk; i += TPB) part += min(gcount[i], CAPC);
#pragma unroll
        for (int o = 1; o < 64; o <<= 1) part += __shfl_xor(part, o, 64);
        if (lane == 0) sm.p2.red[wv] = part;
        sm.p2.cur_[tid] = 0;
        sm.p2.cur_[tid + 256] = 0;
        __syncthreads();
        if (tid == 0)
            sm.p2.bbase = sm.p2.red[0] + sm.p2.red[1] + sm.p2.red[2] + sm.p2.red[3];
        int cntb = min(gcount[bk], CAPC);
        __syncthreads();

        const unsigned int* cbase = &coarse[(size_t)bk * CAPC];
        for (int s = tid; s < cntb; s += TPB)
            atomicAdd(&sm.p2.cur_[cbase[s] & 511], 1);
        __syncthreads();

        if (tid < 64) {          // single-wave scan over 512 counts
            int loc[8];
            int run = 0;
#pragma unroll
            for (int k = 0; k < 8; ++k) { run += sm.p2.cur_[8 * tid + k]; loc[k] = run; }
            int tot = run, sc = run;
#pragma unroll
            for (int o = 1; o < 64; o <<= 1) {
                int t = __shfl_up(sc, o, 64);
                if (tid >= o) sc += t;
            }
            int lex = sc - tot;
#pragma unroll
            for (int k = 0; k < 8; ++k)
                sm.p2.base_[8 * tid + k] = lex + loc[k] - sm.p2.cur_[8 * tid + k];
            if (tid == 63) sm.p2.base_[512] = lex + tot;
        }
        __syncthreads();

        int bbase = sm.p2.bbase;
#pragma unroll
        for (int h = 0; h < 2; ++h) {
            int d = tid + 256 * h;
            int node = (bk << 9) + d;
            if (node < n) {
                cnt[node] = sm.p2.cur_[d];
                off[node] = bbase + sm.p2.base_[d];
            }
        }
        __syncthreads();
#pragma unroll
        for (int h = 0; h < 2; ++h) {
            int d = tid + 256 * h;
            sm.p2.cur_[d] = sm.p2.base_[d];
        }
        __syncthreads();

        for (int s = tid; s < cntb; s += TPB) {
            unsigned int p = cbase[s];
            int d = p & 511;
            int slot = atomicAdd(&sm.p2.cur_[d], 1);
            srow[bbase + slot] = (int)(p >> 9);
        }
        __syncthreads();
    }
    __threadfence();
    grid.sync();

    // ---------------- phase 3: MFMA GEMM ----------------
    const bf16x8* wfv = (const bf16x8*)Wf;
    for (int rt = blockIdx.x; rt < nrt; rt += gridDim.x) {
        int rowBase = rt * 64 + wv * 16;
        int m = rowBase + (lane & 15);
        int mc = (m < n) ? m : (n - 1);
        int kq = (lane >> 4) * 8;

        f32x4 acc[8];
        f32x4 zero = {0.f, 0.f, 0.f, 0.f};
#pragma unroll
        for (int t = 0; t < 8; ++t) acc[t] = zero;

#pragma unroll
        for (int ks = 0; ks < 4; ++ks) {
            int kbase = ks * 32 + kq;
            float4 lo = *(const float4*)&x[(size_t)mc * DCH + kbase];
            float4 hi = *(const float4*)&x[(size_t)mc * DCH + kbase + 4];
            bf16x8 a;
            a[0] = (short)f2bf(lo.x); a[1] = (short)f2bf(lo.y);
            a[2] = (short)f2bf(lo.z); a[3] = (short)f2bf(lo.w);
            a[4] = (short)f2bf(hi.x); a[5] = (short)f2bf(hi.y);
            a[6] = (short)f2bf(hi.z); a[7] = (short)f2bf(hi.w);
#pragma unroll
            for (int nt = 0; nt < 8; ++nt) {
                bf16x8 bfr = wfv[(nt * 4 + ks) * 64 + lane];
                acc[nt] = __builtin_amdgcn_mfma_f32_16x16x32_bf16(a, bfr, acc[nt], 0, 0, 0);
            }
        }

        int orow_base = rowBase + ((lane >> 4) * 4);
#pragma unroll
        for (int r = 0; r < 4; ++r) {
            int orow = orow_base + r;
            if (orow < n) {
                float s = rsqrtf((float)(cnt[orow] + 1));
#pragma unroll
                for (int nt = 0; nt < 8; ++nt) {
                    y[(size_t)orow * DCH + nt * 16 + (lane & 15)] = f2bf(acc[nt][r] * s);
                }
            }
        }
    }
}

// ---------------- per-node gather-aggregate + bias + ReLU (R4/R6 winner) -----
__global__ __launch_bounds__(256) void k_agg(const uint4* __restrict__ y4,
                                             const int* __restrict__ srow,
                                             const int* __restrict__ off,
                                             const float* __restrict__ b,
                                             float* __restrict__ out, int n, int E) {
    int i = blockIdx.x * 4 + (threadIdx.x >> 6);
    if (i >= n) return;
    int lane = threadIdx.x & 63;
    int q = lane >> 4;
    int l16 = lane & 15;
    int s = off[i];
    int e = (i + 1 < n) ? off[i + 1] : E;

    float acc[8];
#pragma unroll
    for (int k = 0; k < 8; ++k) acc[k] = 0.f;

    if (q == 0) {   // self-loop
        uint4 v = y4[(size_t)i * 16 + l16];
        unsigned int p[4] = {v.x, v.y, v.z, v.w};
#pragma unroll
        for (int t = 0; t < 4; ++t) {
            acc[2 * t]     += __uint_as_float(p[t] << 16);
            acc[2 * t + 1] += __uint_as_float(p[t] & 0xffff0000u);
        }
    }

    int j = s;
    for (; j + 8 <= e; j += 8) {
        int s0 = srow[j + q];
        int s1 = srow[j + 4 + q];
        uint4 v0 = y4[(size_t)s0 * 16 + l16];
        uint4 v1 = y4[(size_t)s1 * 16 + l16];
        unsigned int p0[4] = {v0.x, v0.y, v0.z, v0.w};
        unsigned int p1[4] = {v1.x, v1.y, v1.z, v1.w};
#pragma unroll
        for (int t = 0; t < 4; ++t) {
            acc[2 * t]     += __uint_as_float(p0[t] << 16);
            acc[2 * t + 1] += __uint_as_float(p0[t] & 0xffff0000u);
            acc[2 * t]     += __uint_as_float(p1[t] << 16);
            acc[2 * t + 1] += __uint_as_float(p1[t] & 0xffff0000u);
        }
    }
    for (; j + 4 <= e; j += 4) {
        int s0 = srow[j + q];
        uint4 v0 = y4[(size_t)s0 * 16 + l16];
        unsigned int p0[4] = {v0.x, v0.y, v0.z, v0.w};
#pragma unroll
        for (int t = 0; t < 4; ++t) {
            acc[2 * t]     += __uint_as_float(p0[t] << 16);
            acc[2 * t + 1] += __uint_as_float(p0[t] & 0xffff0000u);
        }
    }
    if (j + q < e) {
        int s0 = srow[j + q];
        uint4 v0 = y4[(size_t)s0 * 16 + l16];
        unsigned int p0[4] = {v0.x, v0.y, v0.z, v0.w};
#pragma unroll
        for (int t = 0; t < 4; ++t) {
            acc[2 * t]     += __uint_as_float(p0[t] << 16);
            acc[2 * t + 1] += __uint_as_float(p0[t] & 0xffff0000u);
        }
    }

#pragma unroll
    for (int k = 0; k < 8; ++k) {
        acc[k] += __shfl_xor(acc[k], 16, 64);
        acc[k] += __shfl_xor(acc[k], 32, 64);
    }

    if (q == 0) {
        float sc = rsqrtf((float)(e - s + 1));
        int c0 = l16 * 8;
        float4 b0 = *(const float4*)&b[c0];
        float4 b1 = *(const float4*)&b[c0 + 4];
        float4 o0, o1;
        o0.x = fmaxf(fmaf(sc, acc[0], b0.x), 0.f);
        o0.y = fmaxf(fmaf(sc, acc[1], b0.y), 0.f);
        o0.z = fmaxf(fmaf(sc, acc[2], b0.z), 0.f);
        o0.w = fmaxf(fmaf(sc, acc[3], b0.w), 0.f);
        o1.x = fmaxf(fmaf(sc, acc[4], b1.x), 0.f);
        o1.y = fmaxf(fmaf(sc, acc[5], b1.y), 0.f);
        o1.z = fmaxf(fmaf(sc, acc[6], b1.z), 0.f);
        o1.w = fmaxf(fmaf(sc, acc[7], b1.w), 0.f);
        float4* orow = (float4*)&out[(size_t)i * DCH + c0];
        orow[0] = o0;
        orow[1] = o1;
    }
}

extern "C" void kernel_launch(void* const* d_in, const int* in_sizes, int n_in,
                              void* d_out, int out_size, void* d_ws, size_t ws_size,
                              hipStream_t stream) {
    const float* x = (const float*)d_in[0];
    const int* ei  = (const int*)d_in[1];
    const float* W = (const float*)d_in[2];
    const float* b = (const float*)d_in[3];
    float* out = (float*)d_out;

    int n = in_sizes[0] / DCH;     // 100000
    int E = in_sizes[1] / 2;       // 1600000
    const int* row = ei;           // sources
    const int* col = ei + E;       // destinations

    int B = (n + 511) >> 9;        // 196 coarse buckets (512 nodes each)
    int ntiles = (E + T_PART - 1) / T_PART;  // 782
    int nrt = (n + 63) / 64;       // 1563 gemm row-tiles

    char* ws = (char*)d_ws;
    size_t o = 0;
    auto alloc = [&](size_t bytes) -> void* {
        o = (o + 255) & ~(size_t)255;
        void* p = ws + o;
        o += bytes;
        return p;
    };
    int* cnt     = (int*)alloc((size_t)n * 4);
    int* off     = (int*)alloc((size_t)(n + 1) * 4);
    int* gcount  = (int*)alloc((size_t)B * 4);
    int* srow    = (int*)alloc((size_t)E * 4);
    unsigned int* coarse = (unsigned int*)alloc((size_t)B * CAPC * 4);  // 8.0 MB
    unsigned short* Wf = (unsigned short*)alloc((size_t)DCH * DCH * 2);
    unsigned short* y  = (unsigned short*)alloc((size_t)n * DCH * 2);   // 25.6 MB

    // co-residency: __launch_bounds__(256,4) caps VGPR<=128 -> >=4 blocks/CU;
    // LDS 14.4 KB allows 11. Query to be safe, clamp to 1024 (=4*256 CUs).
    int occ = 4;
    hipOccupancyMaxActiveBlocksPerMultiprocessor(&occ, (const void*)k_mega, TPB, 0);
    int grid = occ * 256;
    if (grid > 1024) grid = 1024;
    if (grid < 256) grid = 256;

    void* args[] = { (void*)&x, (void*)&row, (void*)&col, (void*)&W, (void*)&Wf,
                     (void*)&cnt, (void*)&off, (void*)&gcount, (void*)&coarse,
                     (void*)&srow, (void*)&y, (void*)&n, (void*)&E, (void*)&B,
                     (void*)&ntiles, (void*)&nrt };
    hipLaunchCooperativeKernel((const void*)k_mega, dim3(grid), dim3(TPB),
                               args, 0, stream);
    k_agg<<<(n + 3) / 4, 256, 0, stream>>>((const uint4*)y, srow, off, b, out, n, E);
}